// Round 1
// baseline (759.219 us; speedup 1.0000x reference)
//
#include <hip/hip_runtime.h>
#include <stdint.h>

// Problem constants
#define L_SEQ 2048
#define BB 2
#define DD 1024
#define NH 16
#define SPAN 128

typedef __attribute__((ext_vector_type(8))) short short8;   // 8 x bf16 MFMA frag
typedef __attribute__((ext_vector_type(4))) float floatx4;  // MFMA acc

__device__ __forceinline__ short f32_bf16(float f) {
  uint32_t u = __float_as_uint(f);
  u += 0x7FFFu + ((u >> 16) & 1u);   // RNE
  return (short)(u >> 16);
}

// ---------------- fp32 -> bf16 elementwise (query/key/value) ----------------
__global__ __launch_bounds__(256) void k_convert(
    const float* __restrict__ s0, const float* __restrict__ s1, const float* __restrict__ s2,
    short* __restrict__ d0, short* __restrict__ d1, short* __restrict__ d2) {
  const float* s = blockIdx.y == 0 ? s0 : (blockIdx.y == 1 ? s1 : s2);
  short* d = blockIdx.y == 0 ? d0 : (blockIdx.y == 1 ? d1 : d2);
  int i = blockIdx.x * 256 + threadIdx.x;  // over float4 groups (1048576 total)
  float4 v = ((const float4*)s)[i];
  short4 o;
  o.x = f32_bf16(v.x); o.y = f32_bf16(v.y); o.z = f32_bf16(v.z); o.w = f32_bf16(v.w);
  ((short4*)d)[i] = o;
}

// ---------------- transpose-convert weights (K x N fp32 -> N x K bf16) ------
__global__ __launch_bounds__(256) void k_transpose(
    const float* __restrict__ w0, const float* __restrict__ w1,
    const float* __restrict__ w2, const float* __restrict__ w3,
    short* __restrict__ dst) {
  __shared__ float tile[32][33];
  const float* src = blockIdx.z == 0 ? w0 : blockIdx.z == 1 ? w1 : blockIdx.z == 2 ? w2 : w3;
  short* out = dst + (size_t)blockIdx.z * (DD * DD);
  int bx = blockIdx.x * 32, by = blockIdx.y * 32;
  int tx = threadIdx.x, ty = threadIdx.y;  // block (32,8)
#pragma unroll
  for (int r = 0; r < 32; r += 8)
    tile[ty + r][tx] = src[(size_t)(by + ty + r) * DD + bx + tx];
  __syncthreads();
#pragma unroll
  for (int r = 0; r < 32; r += 8)
    out[(size_t)(bx + ty + r) * DD + by + tx] = f32_bf16(tile[tx][ty + r]);
}

// ---------------- zero-fill the attn output region --------------------------
__global__ __launch_bounds__(256) void k_zero(float4* __restrict__ p) {
  size_t i = (size_t)blockIdx.x * 256 + threadIdx.x;  // 16384 blocks -> 4194304 threads
  float4 z = {0.f, 0.f, 0.f, 0.f};
#pragma unroll
  for (int w = 0; w < 8; ++w) p[i + (size_t)w * 4194304] = z;
}

// ---------------- shared 128x128 bf16 MFMA GEMM core (A row-major, B^T) -----
#define BM 128
#define BN 128
#define BK 32
#define LDK 56  // padded LDS row stride (112 B: 16B-aligned, 2-way bank alias = free)

__device__ __forceinline__ void gemm_core(const short* __restrict__ A,
                                          const short* __restrict__ BT,
                                          floatx4 acc[4][4], int bm0, int bn0) {
  __shared__ short As[BM * LDK];
  __shared__ short Bs[BN * LDK];
  int tid = threadIdx.x;
  int wave = tid >> 6, lane = tid & 63;
  int li = lane & 15, quad = lane >> 4;
  int wm = (wave & 1) * 64, wn = (wave >> 1) * 64;
  int srow = tid >> 1, scol = (tid & 1) * 16;
  const short* gA = A + (size_t)(bm0 + srow) * DD + scol;
  const short* gB = BT + (size_t)(bn0 + srow) * DD + scol;
  short* sA = &As[srow * LDK + scol];
  short* sB = &Bs[srow * LDK + scol];
  for (int k0 = 0; k0 < DD; k0 += BK) {
    short8 a0 = *(const short8*)(gA + k0);
    short8 a1 = *(const short8*)(gA + k0 + 8);
    short8 b0 = *(const short8*)(gB + k0);
    short8 b1 = *(const short8*)(gB + k0 + 8);
    __syncthreads();  // protect previous iter's LDS reads
    *(short8*)sA = a0;
    *(short8*)(sA + 8) = a1;
    *(short8*)sB = b0;
    *(short8*)(sB + 8) = b1;
    __syncthreads();
    short8 af[4], bf[4];
#pragma unroll
    for (int t = 0; t < 4; ++t) {
      af[t] = *(const short8*)&As[(wm + t * 16 + li) * LDK + quad * 8];
      bf[t] = *(const short8*)&Bs[(wn + t * 16 + li) * LDK + quad * 8];
    }
#pragma unroll
    for (int tm = 0; tm < 4; ++tm)
#pragma unroll
      for (int tn = 0; tn < 4; ++tn)
        acc[tm][tn] = __builtin_amdgcn_mfma_f32_16x16x32_bf16(af[tm], bf[tn], acc[tm][tn], 0, 0, 0);
  }
}

// ---------------- fused QKV projection GEMM ---------------------------------
// q,k -> (h,b,l,dk) bf16 ; v -> transposed (h,b,dv,l) bf16
__global__ __launch_bounds__(256) void k_proj(
    const short* __restrict__ xq, const short* __restrict__ xk, const short* __restrict__ xv,
    const short* __restrict__ WT,
    const float* __restrict__ bq, const float* __restrict__ bk, const float* __restrict__ bv,
    short* __restrict__ qo, short* __restrict__ ko, short* __restrict__ vTo) {
  int mode = blockIdx.z;
  const short* A = mode == 0 ? xq : (mode == 1 ? xk : xv);
  const short* BT = WT + (size_t)mode * DD * DD;
  const float* bias = mode == 0 ? bq : (mode == 1 ? bk : bv);
  floatx4 acc[4][4] = {};
  int bm0 = blockIdx.y * BM, bn0 = blockIdx.x * BN;
  gemm_core(A, BT, acc, bm0, bn0);

  int tid = threadIdx.x;
  int wave = tid >> 6, lane = tid & 63;
  int li = lane & 15, quad = lane >> 4;
  int wm = (wave & 1) * 64, wn = (wave >> 1) * 64;
  short* dst01 = (mode == 0) ? qo : ko;
#pragma unroll
  for (int tm = 0; tm < 4; ++tm) {
#pragma unroll
    for (int tn = 0; tn < 4; ++tn) {
      int gn = bn0 + wn + tn * 16 + li;
      float bs = bias[gn];
      int h = gn >> 6, dk = gn & 63;
#pragma unroll
      for (int r = 0; r < 4; ++r) {
        int gm = bm0 + wm + tm * 16 + quad * 4 + r;
        int l = gm >> 1, b = gm & 1;  // rows are l*B + b
        short bvv = f32_bf16(acc[tm][tn][r] + bs);
        if (mode < 2)
          dst01[(((size_t)h * BB + b) * L_SEQ + l) * 64 + dk] = bvv;
        else
          vTo[(((size_t)h * BB + b) * 64 + dk) * L_SEQ + l] = bvv;
      }
    }
  }
}

// ---------------- banded attention: 1 wave per 16 query rows ----------------
// S strip = 17 tiles x 16 cols (j in [i0-128, i0+143]); exact softmax in regs.
__global__ __launch_bounds__(64) void k_attn(
    const short* __restrict__ qw, const short* __restrict__ kw, const short* __restrict__ vTw,
    float* __restrict__ attn_out, short* __restrict__ ctx) {
  __shared__ short P[16 * 296];  // 16 rows x 288 cols (+8 pad), stride 592 B
  const int i0 = blockIdx.x * 16;
  const int hb = blockIdx.y;  // h*B + b
  const int lane = threadIdx.x;
  const int li = lane & 15, quad = lane >> 4;
  const short* Q = qw + (size_t)hb * L_SEQ * 64;
  const short* K = kw + (size_t)hb * L_SEQ * 64;
  const short* VT = vTw + (size_t)hb * 64 * L_SEQ;
  float* Aout = attn_out + (size_t)hb * L_SEQ * L_SEQ;

  short8 qf0 = *(const short8*)(Q + (size_t)(i0 + li) * 64 + quad * 8);
  short8 qf1 = *(const short8*)(Q + (size_t)(i0 + li) * 64 + 32 + quad * 8);

  floatx4 S[17];
  const int jbase = i0 - SPAN;
#pragma unroll
  for (int t = 0; t < 17; ++t) {
    int j0 = jbase + t * 16;
    floatx4 acc = {0.f, 0.f, 0.f, 0.f};
    if (j0 >= 0 && j0 < L_SEQ) {
      const short* kp = K + (size_t)(j0 + li) * 64 + quad * 8;
      short8 kf0 = *(const short8*)kp;
      short8 kf1 = *(const short8*)(kp + 32);
      acc = __builtin_amdgcn_mfma_f32_16x16x32_bf16(qf0, kf0, acc, 0, 0, 0);
      acc = __builtin_amdgcn_mfma_f32_16x16x32_bf16(qf1, kf1, acc, 0, 0, 0);
    }
    S[t] = acc;
  }
  // scale + band mask + row max  (C-layout: row = quad*4+r, col = li)
  float mrow[4] = {-1e30f, -1e30f, -1e30f, -1e30f};
#pragma unroll
  for (int t = 0; t < 17; ++t) {
    int j0 = jbase + t * 16;
    bool tvalid = (j0 >= 0) && (j0 < L_SEQ);
    int j = j0 + li;
#pragma unroll
    for (int r = 0; r < 4; ++r) {
      int i = i0 + quad * 4 + r;
      bool inband = tvalid && (j >= i - SPAN) && (j <= i + SPAN);
      float s = inband ? S[t][r] * 0.125f : -1e30f;
      S[t][r] = s;
      mrow[r] = fmaxf(mrow[r], s);
    }
  }
#pragma unroll
  for (int m = 1; m <= 8; m <<= 1)
#pragma unroll
    for (int r = 0; r < 4; ++r) mrow[r] = fmaxf(mrow[r], __shfl_xor(mrow[r], m));
  float lsum[4] = {0.f, 0.f, 0.f, 0.f};
#pragma unroll
  for (int t = 0; t < 17; ++t)
#pragma unroll
    for (int r = 0; r < 4; ++r) {
      float p = __expf(S[t][r] - mrow[r]);
      S[t][r] = p;
      lsum[r] += p;
    }
#pragma unroll
  for (int m = 1; m <= 8; m <<= 1)
#pragma unroll
    for (int r = 0; r < 4; ++r) lsum[r] += __shfl_xor(lsum[r], m);
  float inv[4];
#pragma unroll
  for (int r = 0; r < 4; ++r) inv[r] = 1.0f / lsum[r];

  // zero LDS pad cols 272..287
#pragma unroll
  for (int c = 0; c < 4; ++c) P[li * 296 + 272 + quad * 4 + c] = 0;
  // write normalized attn (fp32) + stage P (bf16) for PV
#pragma unroll
  for (int t = 0; t < 17; ++t) {
    int j0 = jbase + t * 16;
    bool tvalid = (j0 >= 0) && (j0 < L_SEQ);
#pragma unroll
    for (int r = 0; r < 4; ++r) {
      int irow = quad * 4 + r;
      float p = S[t][r] * inv[r];
      P[irow * 296 + t * 16 + li] = f32_bf16(p);
      if (tvalid) Aout[(size_t)(i0 + irow) * L_SEQ + j0 + li] = p;
    }
  }
  __syncthreads();
  // O = P (16x288) x V (288x64); A-frag from LDS, B-frag direct from V^T global
  floatx4 O[4] = {};
#pragma unroll
  for (int c = 0; c < 9; ++c) {
    short8 pf = *(const short8*)&P[li * 296 + c * 32 + quad * 8];
    int jg = jbase + c * 32 + quad * 8;
    int jc = (jg >= 0 && jg < L_SEQ) ? jg : 0;  // clamp: P is 0 there anyway
#pragma unroll
    for (int n = 0; n < 4; ++n) {
      short8 vf = *(const short8*)(VT + (size_t)(n * 16 + li) * L_SEQ + jc);
      O[n] = __builtin_amdgcn_mfma_f32_16x16x32_bf16(pf, vf, O[n], 0, 0, 0);
    }
  }
  const int b = hb & 1, h = hb >> 1;
#pragma unroll
  for (int n = 0; n < 4; ++n)
#pragma unroll
    for (int r = 0; r < 4; ++r) {
      int irow = quad * 4 + r;
      ctx[((size_t)(i0 + irow) * BB + b) * DD + h * 64 + n * 16 + li] = f32_bf16(O[n][r]);
    }
}

// ---------------- FC GEMM + bias + residual ---------------------------------
__global__ __launch_bounds__(256) void k_fc(
    const short* __restrict__ ctx, const short* __restrict__ WfcT,
    const float* __restrict__ bfc, const float* __restrict__ query,
    float* __restrict__ ypre) {
  floatx4 acc[4][4] = {};
  int bm0 = blockIdx.y * BM, bn0 = blockIdx.x * BN;
  gemm_core(ctx, WfcT, acc, bm0, bn0);
  int tid = threadIdx.x;
  int wave = tid >> 6, lane = tid & 63;
  int li = lane & 15, quad = lane >> 4;
  int wm = (wave & 1) * 64, wn = (wave >> 1) * 64;
#pragma unroll
  for (int tm = 0; tm < 4; ++tm)
#pragma unroll
    for (int tn = 0; tn < 4; ++tn) {
      int gn = bn0 + wn + tn * 16 + li;
      float bs = bfc[gn];
#pragma unroll
      for (int r = 0; r < 4; ++r) {
        int gm = bm0 + wm + tm * 16 + quad * 4 + r;
        ypre[(size_t)gm * DD + gn] = acc[tm][tn][r] + bs + query[(size_t)gm * DD + gn];
      }
    }
}

// ---------------- LayerNorm --------------------------------------------------
__global__ __launch_bounds__(256) void k_ln(
    const float* __restrict__ yp, const float* __restrict__ gamma,
    const float* __restrict__ beta, float* __restrict__ out) {
  __shared__ float red[8];
  int row = blockIdx.x, tid = threadIdx.x;
  float4 v = ((const float4*)(yp + (size_t)row * DD))[tid];
  float s = v.x + v.y + v.z + v.w;
  float s2 = v.x * v.x + v.y * v.y + v.z * v.z + v.w * v.w;
#pragma unroll
  for (int m = 1; m <= 32; m <<= 1) {
    s += __shfl_xor(s, m);
    s2 += __shfl_xor(s2, m);
  }
  int wv = tid >> 6;
  if ((tid & 63) == 0) { red[wv] = s; red[wv + 4] = s2; }
  __syncthreads();
  s = red[0] + red[1] + red[2] + red[3];
  s2 = red[4] + red[5] + red[6] + red[7];
  float mu = s * (1.0f / DD);
  float var = s2 * (1.0f / DD) - mu * mu;
  float rs = rsqrtf(var + 1e-5f);
  float4 g = ((const float4*)gamma)[tid];
  float4 bb = ((const float4*)beta)[tid];
  float4 o;
  o.x = (v.x - mu) * rs * g.x + bb.x;
  o.y = (v.y - mu) * rs * g.y + bb.y;
  o.z = (v.z - mu) * rs * g.z + bb.z;
  o.w = (v.w - mu) * rs * g.w + bb.w;
  ((float4*)(out + (size_t)row * DD))[tid] = o;
}

// ---------------- launch -----------------------------------------------------
extern "C" void kernel_launch(void* const* d_in, const int* in_sizes, int n_in,
                              void* d_out, int out_size, void* d_ws, size_t ws_size,
                              hipStream_t stream) {
  const float* query = (const float*)d_in[0];
  const float* key   = (const float*)d_in[1];
  const float* value = (const float*)d_in[2];
  const float* Wq    = (const float*)d_in[3];
  const float* bq    = (const float*)d_in[4];
  const float* Wk    = (const float*)d_in[5];
  const float* bk    = (const float*)d_in[6];
  const float* Wv    = (const float*)d_in[7];
  const float* bv    = (const float*)d_in[8];
  const float* Wfc   = (const float*)d_in[9];
  const float* bfc   = (const float*)d_in[10];
  const float* gamma = (const float*)d_in[11];
  const float* beta  = (const float*)d_in[12];
  float* out = (float*)d_out;
  float* attn = out + (size_t)L_SEQ * BB * DD;  // y first (4194304), then attn

  // workspace layout (needs 80 MB)
  char* w = (char*)d_ws;
  short* xq_b  = (short*)(w);
  short* xk_b  = (short*)(w + ((size_t)8 << 20));
  short* xv_b  = (short*)(w + ((size_t)16 << 20));
  short* WT    = (short*)(w + ((size_t)24 << 20));  // WqT,WkT,WvT,WfcT bf16 (2MB each)
  short* q_ws  = (short*)(w + ((size_t)32 << 20));
  short* k_ws  = (short*)(w + ((size_t)40 << 20));
  short* vT_ws = (short*)(w + ((size_t)48 << 20));
  short* ctx   = (short*)(w + ((size_t)56 << 20));
  float* ypre  = (float*)(w + ((size_t)64 << 20));

  k_convert<<<dim3(4096, 3), 256, 0, stream>>>(query, key, value, xq_b, xk_b, xv_b);
  k_transpose<<<dim3(32, 32, 4), dim3(32, 8), 0, stream>>>(Wq, Wk, Wv, Wfc, WT);
  k_zero<<<16384, 256, 0, stream>>>((float4*)attn);
  k_proj<<<dim3(8, 32, 3), 256, 0, stream>>>(xq_b, xk_b, xv_b, WT, bq, bk, bv, q_ws, k_ws, vT_ws);
  k_attn<<<dim3(128, 32), 64, 0, stream>>>(q_ws, k_ws, vT_ws, attn, ctx);
  k_fc<<<dim3(8, 32), 256, 0, stream>>>(ctx, WT + (size_t)3 * DD * DD, bfc, query, ypre);
  k_ln<<<4096, 256, 0, stream>>>(ypre, gamma, beta, out);
}

// Round 2
// 720.131 us; speedup vs baseline: 1.0543x; 1.0543x over previous
//
#include <hip/hip_runtime.h>
#include <stdint.h>

// Problem constants
#define L_SEQ 2048
#define BB 2
#define DD 1024
#define NH 16
#define SPAN 128

typedef __attribute__((ext_vector_type(8))) short short8;   // 8 x bf16 MFMA frag
typedef __attribute__((ext_vector_type(4))) float floatx4;  // MFMA acc

__device__ __forceinline__ short f32_bf16(float f) {
  uint32_t u = __float_as_uint(f);
  u += 0x7FFFu + ((u >> 16) & 1u);   // RNE
  return (short)(u >> 16);
}
__device__ __forceinline__ float bf2f(short s) {
  return __uint_as_float(((uint32_t)(uint16_t)s) << 16);
}

// async 16B global->LDS (direct-to-shared DMA; LDS dest = wave base + lane*16)
__device__ __forceinline__ void gld16(const short* g, short* l) {
  __builtin_amdgcn_global_load_lds(
      (__attribute__((address_space(1))) void*)(g),
      (__attribute__((address_space(3))) void*)(l), 16, 0, 0);
}

// ---------------- fp32 -> bf16 elementwise (query/key/value) ----------------
__global__ __launch_bounds__(256) void k_convert(
    const float* __restrict__ s0, const float* __restrict__ s1, const float* __restrict__ s2,
    short* __restrict__ d0, short* __restrict__ d1, short* __restrict__ d2) {
  const float* s = blockIdx.y == 0 ? s0 : (blockIdx.y == 1 ? s1 : s2);
  short* d = blockIdx.y == 0 ? d0 : (blockIdx.y == 1 ? d1 : d2);
  int i = blockIdx.x * 256 + threadIdx.x;  // over float4 groups (1048576 total)
  float4 v = ((const float4*)s)[i];
  short4 o;
  o.x = f32_bf16(v.x); o.y = f32_bf16(v.y); o.z = f32_bf16(v.z); o.w = f32_bf16(v.w);
  ((short4*)d)[i] = o;
}

// ---------------- transpose-convert weights (K x N fp32 -> N x K bf16) ------
__global__ __launch_bounds__(256) void k_transpose(
    const float* __restrict__ w0, const float* __restrict__ w1,
    const float* __restrict__ w2, const float* __restrict__ w3,
    short* __restrict__ dst) {
  __shared__ float tile[32][33];
  const float* src = blockIdx.z == 0 ? w0 : blockIdx.z == 1 ? w1 : blockIdx.z == 2 ? w2 : w3;
  short* out = dst + (size_t)blockIdx.z * (DD * DD);
  int bx = blockIdx.x * 32, by = blockIdx.y * 32;
  int tx = threadIdx.x, ty = threadIdx.y;  // block (32,8)
#pragma unroll
  for (int r = 0; r < 32; r += 8)
    tile[ty + r][tx] = src[(size_t)(by + ty + r) * DD + bx + tx];
  __syncthreads();
#pragma unroll
  for (int r = 0; r < 32; r += 8)
    out[(size_t)(bx + ty + r) * DD + by + tx] = f32_bf16(tile[tx][ty + r]);
}

// ---------------- m97-style 128x128 bf16 MFMA GEMM core (A row-major, B^T) --
#define BM 128
#define BN 128
#define BK 32

__device__ __forceinline__ void gemm_core(const short* __restrict__ A,
                                          const short* __restrict__ BT,
                                          floatx4 acc[4][4], int bm0, int bn0) {
  __shared__ short As[BM * BK];  // 8 KB, row-major 128x32, no pad (global_load_lds)
  __shared__ short Bs[BN * BK];
  int tid = threadIdx.x;
  int wave = tid >> 6, lane = tid & 63;
  int li = lane & 15, quad = lane >> 4;
  int wm = (wave & 1) * 64, wn = (wave >> 1) * 64;
  // staging: wave stages rows [wave*32, wave*32+32); lane -> row lane/4, col (lane&3)*8
  int srow = wave * 32 + (lane >> 2);
  int scol = (lane & 3) * 8;
  const short* gA = A + (size_t)(bm0 + srow) * DD + scol;
  const short* gB = BT + (size_t)(bn0 + srow) * DD + scol;
  short* lA = &As[wave * 32 * BK];  // wave-uniform LDS base
  short* lB = &Bs[wave * 32 * BK];
  for (int k0 = 0; k0 < DD; k0 += BK) {
    __syncthreads();  // previous iter's LDS reads done before overwrite
    gld16(gA + k0, lA);
    gld16(gA + (size_t)16 * DD + k0, lA + 16 * BK);
    gld16(gB + k0, lB);
    gld16(gB + (size_t)16 * DD + k0, lB + 16 * BK);
    __syncthreads();  // staging visible (vmcnt(0) drained by barrier)
    short8 af[4], bf[4];
#pragma unroll
    for (int t = 0; t < 4; ++t) {
      af[t] = *(const short8*)&As[(wm + t * 16 + li) * BK + quad * 8];
      bf[t] = *(const short8*)&Bs[(wn + t * 16 + li) * BK + quad * 8];
    }
#pragma unroll
    for (int tm = 0; tm < 4; ++tm)
#pragma unroll
      for (int tn = 0; tn < 4; ++tn)
        acc[tm][tn] = __builtin_amdgcn_mfma_f32_16x16x32_bf16(af[tm], bf[tn], acc[tm][tn], 0, 0, 0);
  }
}

// ---------------- fused QKV projection GEMM ---------------------------------
// q,k,v -> (h,b,l,dk) bf16 (v transposed later by k_vt)
__global__ __launch_bounds__(256) void k_proj(
    const short* __restrict__ xq, const short* __restrict__ xk, const short* __restrict__ xv,
    const short* __restrict__ WT,
    const float* __restrict__ bq, const float* __restrict__ bk, const float* __restrict__ bv,
    short* __restrict__ qo, short* __restrict__ ko, short* __restrict__ vo) {
  int mode = blockIdx.z;
  const short* A = mode == 0 ? xq : (mode == 1 ? xk : xv);
  const short* BT = WT + (size_t)mode * DD * DD;
  const float* bias = mode == 0 ? bq : (mode == 1 ? bk : bv);
  floatx4 acc[4][4] = {};
  int bm0 = blockIdx.y * BM, bn0 = blockIdx.x * BN;
  gemm_core(A, BT, acc, bm0, bn0);

  int tid = threadIdx.x;
  int wave = tid >> 6, lane = tid & 63;
  int li = lane & 15, quad = lane >> 4;
  int wm = (wave & 1) * 64, wn = (wave >> 1) * 64;
  short* dst = (mode == 0) ? qo : (mode == 1 ? ko : vo);
#pragma unroll
  for (int tm = 0; tm < 4; ++tm) {
#pragma unroll
    for (int tn = 0; tn < 4; ++tn) {
      int gn = bn0 + wn + tn * 16 + li;
      float bs = bias[gn];
      int h = gn >> 6, dk = gn & 63;
#pragma unroll
      for (int r = 0; r < 4; ++r) {
        int gm = bm0 + wm + tm * 16 + quad * 4 + r;
        int l = gm >> 1, b = gm & 1;  // rows are l*B + b
        dst[(((size_t)h * BB + b) * L_SEQ + l) * 64 + dk] = f32_bf16(acc[tm][tn][r] + bs);
      }
    }
  }
}

// ---------------- transpose v: (h,b,l,dv) -> (h,b,dv,l) ---------------------
__global__ __launch_bounds__(256) void k_vt(const short* __restrict__ vl, short* __restrict__ vt) {
  __shared__ short tl[64][72];
  int l0 = blockIdx.x * 64, hb = blockIdx.y;
  const short* src = vl + ((size_t)hb * L_SEQ + l0) * 64;
  short* dst = vt + (size_t)hb * 64 * L_SEQ + l0;
  int tid = threadIdx.x;
  int r = tid >> 2, c0 = (tid & 3) * 16;
  *(short8*)&tl[r][c0] = *(const short8*)(src + (size_t)r * 64 + c0);
  *(short8*)&tl[r][c0 + 8] = *(const short8*)(src + (size_t)r * 64 + c0 + 8);
  __syncthreads();
  int d = tid >> 2, lb = (tid & 3) * 16;
  short8 o0, o1;
#pragma unroll
  for (int j = 0; j < 8; ++j) o0[j] = tl[lb + j][d];
#pragma unroll
  for (int j = 0; j < 8; ++j) o1[j] = tl[lb + 8 + j][d];
  *(short8*)(dst + (size_t)d * L_SEQ + lb) = o0;
  *(short8*)(dst + (size_t)d * L_SEQ + lb + 8) = o1;
}

// ---------------- banded attention: 4 waves/block, 16 query rows per wave ---
// Writes FULL attn rows (zeros outside band) coalesced -> no separate zero-fill.
__global__ __launch_bounds__(256) void k_attn(
    const short* __restrict__ qw, const short* __restrict__ kw, const short* __restrict__ vTw,
    float* __restrict__ attn_out, short* __restrict__ ctx) {
  __shared__ short P[4][16 * 296];  // per-wave bf16 strip: 16 rows x 288 cols (+8 pad)
  const int wv = threadIdx.x >> 6, lane = threadIdx.x & 63;
  const int li = lane & 15, quad = lane >> 4;
  const int i0 = blockIdx.x * 64 + wv * 16;
  const int hb = blockIdx.y;  // h*B + b
  const short* Q = qw + (size_t)hb * L_SEQ * 64;
  const short* K = kw + (size_t)hb * L_SEQ * 64;
  const short* VT = vTw + (size_t)hb * 64 * L_SEQ;
  float* Aout = attn_out + (size_t)hb * L_SEQ * L_SEQ;

  short8 qf0 = *(const short8*)(Q + (size_t)(i0 + li) * 64 + quad * 8);
  short8 qf1 = *(const short8*)(Q + (size_t)(i0 + li) * 64 + 32 + quad * 8);

  floatx4 S[17];
  const int jbase = i0 - SPAN;
#pragma unroll
  for (int t = 0; t < 17; ++t) {
    int j0 = jbase + t * 16;
    floatx4 acc = {0.f, 0.f, 0.f, 0.f};
    if (j0 >= 0 && j0 < L_SEQ) {
      const short* kp = K + (size_t)(j0 + li) * 64 + quad * 8;
      short8 kf0 = *(const short8*)kp;
      short8 kf1 = *(const short8*)(kp + 32);
      acc = __builtin_amdgcn_mfma_f32_16x16x32_bf16(qf0, kf0, acc, 0, 0, 0);
      acc = __builtin_amdgcn_mfma_f32_16x16x32_bf16(qf1, kf1, acc, 0, 0, 0);
    }
    S[t] = acc;
  }
  // scale + band mask + row max  (C-layout: row = quad*4+r, col = li)
  float mrow[4] = {-1e30f, -1e30f, -1e30f, -1e30f};
#pragma unroll
  for (int t = 0; t < 17; ++t) {
    int j0 = jbase + t * 16;
    bool tvalid = (j0 >= 0) && (j0 < L_SEQ);
    int j = j0 + li;
#pragma unroll
    for (int r = 0; r < 4; ++r) {
      int i = i0 + quad * 4 + r;
      bool inband = tvalid && (j >= i - SPAN) && (j <= i + SPAN);
      float s = inband ? S[t][r] * 0.125f : -1e30f;
      S[t][r] = s;
      mrow[r] = fmaxf(mrow[r], s);
    }
  }
#pragma unroll
  for (int m = 1; m <= 8; m <<= 1)
#pragma unroll
    for (int r = 0; r < 4; ++r) mrow[r] = fmaxf(mrow[r], __shfl_xor(mrow[r], m));
  float lsum[4] = {0.f, 0.f, 0.f, 0.f};
#pragma unroll
  for (int t = 0; t < 17; ++t)
#pragma unroll
    for (int r = 0; r < 4; ++r) {
      float p = __expf(S[t][r] - mrow[r]);
      S[t][r] = p;
      lsum[r] += p;
    }
#pragma unroll
  for (int m = 1; m <= 8; m <<= 1)
#pragma unroll
    for (int r = 0; r < 4; ++r) lsum[r] += __shfl_xor(lsum[r], m);
  float inv[4];
#pragma unroll
  for (int r = 0; r < 4; ++r) inv[r] = 1.0f / lsum[r];

  // stage normalized p (bf16) into strip; out-of-band entries are exactly 0
  short* myP = P[wv];
#pragma unroll
  for (int t = 0; t < 17; ++t)
#pragma unroll
    for (int r = 0; r < 4; ++r)
      myP[(quad * 4 + r) * 296 + t * 16 + li] = f32_bf16(S[t][r] * inv[r]);
  // zero pad cols 272..287 (each lane one short4)
  *(short4*)&myP[(lane >> 2) * 296 + 272 + (lane & 3) * 4] = short4{0, 0, 0, 0};
  __syncthreads();

  // O = P (16x288) x V (288x64); A-frag from LDS strip, B-frag from V^T global
  floatx4 O[4] = {};
#pragma unroll
  for (int c = 0; c < 9; ++c) {
    short8 pf = *(const short8*)&myP[li * 296 + c * 32 + quad * 8];
    int jg = jbase + c * 32 + quad * 8;
    int jc = (jg >= 0 && jg < L_SEQ) ? jg : 0;  // clamp: P is 0 there anyway
#pragma unroll
    for (int n = 0; n < 4; ++n) {
      short8 vf = *(const short8*)(VT + (size_t)(n * 16 + li) * L_SEQ + jc);
      O[n] = __builtin_amdgcn_mfma_f32_16x16x32_bf16(pf, vf, O[n], 0, 0, 0);
    }
  }
  const int b = hb & 1, h = hb >> 1;
#pragma unroll
  for (int n = 0; n < 4; ++n)
#pragma unroll
    for (int r = 0; r < 4; ++r) {
      int irow = quad * 4 + r;
      ctx[((size_t)(i0 + irow) * BB + b) * DD + h * 64 + n * 16 + li] = f32_bf16(O[n][r]);
    }

  // coalesced full-row attn writes: 16 rows x 2048 cols fp32 per wave
#pragma unroll 4
  for (int row = 0; row < 16; ++row) {
    float* orow = Aout + (size_t)(i0 + row) * L_SEQ;
    const short* prow = &myP[row * 296];
#pragma unroll
    for (int it = 0; it < 8; ++it) {
      int col = it * 256 + lane * 4;
      int s = col - jbase;
      float4 v = {0.f, 0.f, 0.f, 0.f};
      if (s >= 0 && s < 288) {
        short4 p4 = *(const short4*)(prow + s);
        v.x = bf2f(p4.x); v.y = bf2f(p4.y); v.z = bf2f(p4.z); v.w = bf2f(p4.w);
      }
      *(float4*)(orow + col) = v;
    }
  }
}

// ---------------- FC GEMM + bias + residual ---------------------------------
__global__ __launch_bounds__(256) void k_fc(
    const short* __restrict__ ctx, const short* __restrict__ WfcT,
    const float* __restrict__ bfc, const float* __restrict__ query,
    float* __restrict__ ypre) {
  floatx4 acc[4][4] = {};
  int bm0 = blockIdx.y * BM, bn0 = blockIdx.x * BN;
  gemm_core(ctx, WfcT, acc, bm0, bn0);
  int tid = threadIdx.x;
  int wave = tid >> 6, lane = tid & 63;
  int li = lane & 15, quad = lane >> 4;
  int wm = (wave & 1) * 64, wn = (wave >> 1) * 64;
#pragma unroll
  for (int tm = 0; tm < 4; ++tm)
#pragma unroll
    for (int tn = 0; tn < 4; ++tn) {
      int gn = bn0 + wn + tn * 16 + li;
      float bs = bfc[gn];
#pragma unroll
      for (int r = 0; r < 4; ++r) {
        int gm = bm0 + wm + tm * 16 + quad * 4 + r;
        ypre[(size_t)gm * DD + gn] = acc[tm][tn][r] + bs + query[(size_t)gm * DD + gn];
      }
    }
}

// ---------------- LayerNorm --------------------------------------------------
__global__ __launch_bounds__(256) void k_ln(
    const float* __restrict__ yp, const float* __restrict__ gamma,
    const float* __restrict__ beta, float* __restrict__ out) {
  __shared__ float red[8];
  int row = blockIdx.x, tid = threadIdx.x;
  float4 v = ((const float4*)(yp + (size_t)row * DD))[tid];
  float s = v.x + v.y + v.z + v.w;
  float s2 = v.x * v.x + v.y * v.y + v.z * v.z + v.w * v.w;
#pragma unroll
  for (int m = 1; m <= 32; m <<= 1) {
    s += __shfl_xor(s, m);
    s2 += __shfl_xor(s2, m);
  }
  int wv = tid >> 6;
  if ((tid & 63) == 0) { red[wv] = s; red[wv + 4] = s2; }
  __syncthreads();
  s = red[0] + red[1] + red[2] + red[3];
  s2 = red[4] + red[5] + red[6] + red[7];
  float mu = s * (1.0f / DD);
  float var = s2 * (1.0f / DD) - mu * mu;
  float rs = rsqrtf(var + 1e-5f);
  float4 g = ((const float4*)gamma)[tid];
  float4 bb = ((const float4*)beta)[tid];
  float4 o;
  o.x = (v.x - mu) * rs * g.x + bb.x;
  o.y = (v.y - mu) * rs * g.y + bb.y;
  o.z = (v.z - mu) * rs * g.z + bb.z;
  o.w = (v.w - mu) * rs * g.w + bb.w;
  ((float4*)(out + (size_t)row * DD))[tid] = o;
}

// ---------------- launch -----------------------------------------------------
extern "C" void kernel_launch(void* const* d_in, const int* in_sizes, int n_in,
                              void* d_out, int out_size, void* d_ws, size_t ws_size,
                              hipStream_t stream) {
  const float* query = (const float*)d_in[0];
  const float* key   = (const float*)d_in[1];
  const float* value = (const float*)d_in[2];
  const float* Wq    = (const float*)d_in[3];
  const float* bq    = (const float*)d_in[4];
  const float* Wk    = (const float*)d_in[5];
  const float* bk    = (const float*)d_in[6];
  const float* Wv    = (const float*)d_in[7];
  const float* bv    = (const float*)d_in[8];
  const float* Wfc   = (const float*)d_in[9];
  const float* bfc   = (const float*)d_in[10];
  const float* gamma = (const float*)d_in[11];
  const float* beta  = (const float*)d_in[12];
  float* out = (float*)d_out;
  float* attn = out + (size_t)L_SEQ * BB * DD;  // y first (4194304), then attn

  // workspace layout (88 MB)
  char* w = (char*)d_ws;
  short* xq_b  = (short*)(w);
  short* xk_b  = (short*)(w + ((size_t)8 << 20));
  short* xv_b  = (short*)(w + ((size_t)16 << 20));
  short* WT    = (short*)(w + ((size_t)24 << 20));  // WqT,WkT,WvT,WfcT bf16 (2MB each)
  short* q_ws  = (short*)(w + ((size_t)32 << 20));
  short* k_ws  = (short*)(w + ((size_t)40 << 20));
  short* v_lin = (short*)(w + ((size_t)48 << 20));
  short* vT_ws = (short*)(w + ((size_t)56 << 20));
  short* ctx   = (short*)(w + ((size_t)64 << 20));
  float* ypre  = (float*)(w + ((size_t)72 << 20));

  k_convert<<<dim3(4096, 3), 256, 0, stream>>>(query, key, value, xq_b, xk_b, xv_b);
  k_transpose<<<dim3(32, 32, 4), dim3(32, 8), 0, stream>>>(Wq, Wk, Wv, Wfc, WT);
  k_proj<<<dim3(8, 32, 3), 256, 0, stream>>>(xq_b, xk_b, xv_b, WT, bq, bk, bv, q_ws, k_ws, v_lin);
  k_vt<<<dim3(32, 32), 256, 0, stream>>>(v_lin, vT_ws);
  k_attn<<<dim3(32, 32), 256, 0, stream>>>(q_ws, k_ws, vT_ws, attn, ctx);
  k_fc<<<dim3(8, 32), 256, 0, stream>>>(ctx, WT + (size_t)3 * DD * DD, bfc, query, ypre);
  k_ln<<<4096, 256, 0, stream>>>(ypre, gamma, beta, out);
}

// Round 4
// 706.923 us; speedup vs baseline: 1.0740x; 1.0187x over previous
//
#include <hip/hip_runtime.h>
#include <stdint.h>

// Problem constants
#define L_SEQ 2048
#define BB 2
#define DD 1024
#define NH 16
#define SPAN 128

typedef __attribute__((ext_vector_type(8))) short short8;   // 8 x bf16 MFMA frag
typedef __attribute__((ext_vector_type(4))) float floatx4;  // MFMA acc / NT stores

__device__ __forceinline__ short f32_bf16(float f) {
  uint32_t u = __float_as_uint(f);
  u += 0x7FFFu + ((u >> 16) & 1u);   // RNE
  return (short)(u >> 16);
}
__device__ __forceinline__ float bf2f(short s) {
  return __uint_as_float(((uint32_t)(uint16_t)s) << 16);
}

// async 16B global->LDS (LDS dest = wave-uniform base + lane*16)
__device__ __forceinline__ void gld16(const short* g, short* l) {
  __builtin_amdgcn_global_load_lds(
      (__attribute__((address_space(1))) void*)(g),
      (__attribute__((address_space(3))) void*)(l), 16, 0, 0);
}

// ---------------- prep: convert q/k/v to bf16 + transpose-convert weights ---
__global__ __launch_bounds__(256) void k_prep(
    const float* __restrict__ s0, const float* __restrict__ s1, const float* __restrict__ s2,
    const float* __restrict__ w0, const float* __restrict__ w1,
    const float* __restrict__ w2, const float* __restrict__ w3,
    short* __restrict__ d0, short* __restrict__ d1, short* __restrict__ d2,
    short* __restrict__ WT) {
  __shared__ float tile[32][33];
  int bid = blockIdx.x, tid = threadIdx.x;
  if (bid < 12288) {  // convert: 3 tensors x 4096 blocks x 256 float4
    int y = bid >> 12;  // 0..2  (bid/4096)
    const float* s = y == 0 ? s0 : (y == 1 ? s1 : s2);
    short* d = y == 0 ? d0 : (y == 1 ? d1 : d2);
    int i = (bid & 4095) * 256 + tid;
    float4 v = ((const float4*)s)[i];
    short4 o;
    o.x = f32_bf16(v.x); o.y = f32_bf16(v.y); o.z = f32_bf16(v.z); o.w = f32_bf16(v.w);
    ((short4*)d)[i] = o;
  } else {  // transpose: 4 weights x 1024 blocks (32x32 tiles)
    int b2 = bid - 12288;
    int z = b2 >> 10;
    int xy = b2 & 1023;
    int bx = (xy & 31) * 32, by = (xy >> 5) * 32;
    int tx = tid & 31, ty = tid >> 5;  // (32,8)
    const float* src = z == 0 ? w0 : z == 1 ? w1 : z == 2 ? w2 : w3;
    short* out = WT + (size_t)z * (DD * DD);
#pragma unroll
    for (int r = 0; r < 32; r += 8)
      tile[ty + r][tx] = src[(size_t)(by + ty + r) * DD + bx + tx];
    __syncthreads();
#pragma unroll
    for (int r = 0; r < 32; r += 8)
      out[(size_t)(bx + ty + r) * DD + by + tx] = f32_bf16(tile[tx][ty + r]);
  }
}

// -------- 128x128 bf16 MFMA GEMM core, BK=64 via 4x (128x32) LDS tiles ------
#define BM 128
#define BN 128

__device__ __forceinline__ void gemm_core(const short* __restrict__ A,
                                          const short* __restrict__ BT,
                                          floatx4 acc[4][4], int bm0, int bn0) {
  __shared__ short As0[BM * 32], As1[BM * 32];  // k-halves, stride-32 rows
  __shared__ short Bs0[BN * 32], Bs1[BN * 32];  // total 32 KB
  int tid = threadIdx.x;
  int wave = tid >> 6, lane = tid & 63;
  int li = lane & 15, quad = lane >> 4;
  int wm = (wave & 1) * 64, wn = (wave >> 1) * 64;
  int r0 = wave * 32 + (lane >> 2);  // staging row, col (lane&3)*8
  int c0 = (lane & 3) * 8;
  const short* gA = A + (size_t)(bm0 + r0) * DD + c0;
  const short* gB = BT + (size_t)(bn0 + r0) * DD + c0;
  short* lA0 = &As0[wave * 32 * 32];
  short* lA1 = &As1[wave * 32 * 32];
  short* lB0 = &Bs0[wave * 32 * 32];
  short* lB1 = &Bs1[wave * 32 * 32];
  for (int k0 = 0; k0 < DD; k0 += 64) {
    __syncthreads();  // prior LDS reads complete
    gld16(gA + k0, lA0);
    gld16(gA + (size_t)16 * DD + k0, lA0 + 16 * 32);
    gld16(gA + k0 + 32, lA1);
    gld16(gA + (size_t)16 * DD + k0 + 32, lA1 + 16 * 32);
    gld16(gB + k0, lB0);
    gld16(gB + (size_t)16 * DD + k0, lB0 + 16 * 32);
    gld16(gB + k0 + 32, lB1);
    gld16(gB + (size_t)16 * DD + k0 + 32, lB1 + 16 * 32);
    __syncthreads();  // staging visible
    short8 af[4], bf[4];
#pragma unroll
    for (int t = 0; t < 4; ++t) {
      af[t] = *(const short8*)&As0[(wm + t * 16 + li) * 32 + quad * 8];
      bf[t] = *(const short8*)&Bs0[(wn + t * 16 + li) * 32 + quad * 8];
    }
#pragma unroll
    for (int tm = 0; tm < 4; ++tm)
#pragma unroll
      for (int tn = 0; tn < 4; ++tn)
        acc[tm][tn] = __builtin_amdgcn_mfma_f32_16x16x32_bf16(af[tm], bf[tn], acc[tm][tn], 0, 0, 0);
#pragma unroll
    for (int t = 0; t < 4; ++t) {
      af[t] = *(const short8*)&As1[(wm + t * 16 + li) * 32 + quad * 8];
      bf[t] = *(const short8*)&Bs1[(wn + t * 16 + li) * 32 + quad * 8];
    }
#pragma unroll
    for (int tm = 0; tm < 4; ++tm)
#pragma unroll
      for (int tn = 0; tn < 4; ++tn)
        acc[tm][tn] = __builtin_amdgcn_mfma_f32_16x16x32_bf16(af[tm], bf[tn], acc[tm][tn], 0, 0, 0);
  }
}

// ---------------- fused QKV projection GEMM ---------------------------------
__global__ __launch_bounds__(256) void k_proj(
    const short* __restrict__ xq, const short* __restrict__ xk, const short* __restrict__ xv,
    const short* __restrict__ WT,
    const float* __restrict__ bq, const float* __restrict__ bk, const float* __restrict__ bv,
    short* __restrict__ qo, short* __restrict__ ko, short* __restrict__ vo) {
  int mode = blockIdx.z;
  const short* A = mode == 0 ? xq : (mode == 1 ? xk : xv);
  const short* BT = WT + (size_t)mode * DD * DD;
  const float* bias = mode == 0 ? bq : (mode == 1 ? bk : bv);
  floatx4 acc[4][4] = {};
  int bm0 = blockIdx.y * BM, bn0 = blockIdx.x * BN;
  gemm_core(A, BT, acc, bm0, bn0);

  int tid = threadIdx.x;
  int wave = tid >> 6, lane = tid & 63;
  int li = lane & 15, quad = lane >> 4;
  int wm = (wave & 1) * 64, wn = (wave >> 1) * 64;
  short* dst = (mode == 0) ? qo : (mode == 1 ? ko : vo);
#pragma unroll
  for (int tm = 0; tm < 4; ++tm) {
#pragma unroll
    for (int tn = 0; tn < 4; ++tn) {
      int gn = bn0 + wn + tn * 16 + li;
      float bs = bias[gn];
      int h = gn >> 6, dk = gn & 63;
#pragma unroll
      for (int r = 0; r < 4; ++r) {
        int gm = bm0 + wm + tm * 16 + quad * 4 + r;
        int l = gm >> 1, b = gm & 1;  // rows are l*B + b
        dst[(((size_t)h * BB + b) * L_SEQ + l) * 64 + dk] = f32_bf16(acc[tm][tn][r] + bs);
      }
    }
  }
}

// ---------------- transpose v: (h,b,l,dv) -> (h,b,dv,l) ---------------------
__global__ __launch_bounds__(256) void k_vt(const short* __restrict__ vl, short* __restrict__ vt) {
  __shared__ short tl[64][72];
  int l0 = blockIdx.x * 64, hb = blockIdx.y;
  const short* src = vl + ((size_t)hb * L_SEQ + l0) * 64;
  short* dst = vt + (size_t)hb * 64 * L_SEQ + l0;
  int tid = threadIdx.x;
  int r = tid >> 2, c0 = (tid & 3) * 16;
  *(short8*)&tl[r][c0] = *(const short8*)(src + (size_t)r * 64 + c0);
  *(short8*)&tl[r][c0 + 8] = *(const short8*)(src + (size_t)r * 64 + c0 + 8);
  __syncthreads();
  int d = tid >> 2, lb = (tid & 3) * 16;
  short8 o0, o1;
#pragma unroll
  for (int j = 0; j < 8; ++j) o0[j] = tl[lb + j][d];
#pragma unroll
  for (int j = 0; j < 8; ++j) o1[j] = tl[lb + 8 + j][d];
  *(short8*)(dst + (size_t)d * L_SEQ + lb) = o0;
  *(short8*)(dst + (size_t)d * L_SEQ + lb + 8) = o1;
}

// ---------------- banded attention: block = 4 waves = 64 q rows -------------
// Cooperative K-window staging (320x64 -> 40 KB LDS), LDS reused for P strips.
__global__ __launch_bounds__(256) void k_attn(
    const short* __restrict__ qw, const short* __restrict__ kw, const short* __restrict__ vTw,
    float* __restrict__ attn_out, short* __restrict__ ctx) {
  __shared__ short sbuf[20480];  // 40960 B: K0[320*32] | K1[320*32]; later P[4][16*296]
  short* K0 = sbuf;
  short* K1 = sbuf + 10240;
  const int tid = threadIdx.x;
  const int wv = tid >> 6, lane = tid & 63;
  const int li = lane & 15, quad = lane >> 4;
  const int i0b = blockIdx.x * 64;
  const int i0 = i0b + wv * 16;
  const int jb = i0b - SPAN;  // K window rows jb .. jb+319
  const int hb = blockIdx.y;  // h*B + b
  const short* Q = qw + (size_t)hb * L_SEQ * 64;
  const short* K = kw + (size_t)hb * L_SEQ * 64;
  const short* VT = vTw + (size_t)hb * 64 * L_SEQ;
  float* Aout = attn_out + (size_t)hb * L_SEQ * L_SEQ;

  // ---- stage K window: 40 wave-instrs (10/wave); lane-linear LDS layout ----
#pragma unroll
  for (int t = 0; t < 10; ++t) {
    int idx = wv + 4 * t;           // 0..39 (uniform per wave)
    int half = idx >= 20 ? 1 : 0;   // K0 / K1 (k-cols 0..31 / 32..63)
    int ridx = idx - half * 20;     // 0..19 -> rows ridx*16 .. +16
    int row = ridx * 16 + (lane >> 2);
    int jr = jb + row;
    int jc = jr < 0 ? 0 : (jr >= L_SEQ ? L_SEQ - 1 : jr);  // clamp (masked later)
    const short* g = K + (size_t)jc * 64 + half * 32 + (lane & 3) * 8;
    short* l = (half ? K1 : K0) + ridx * 16 * 32;  // wave-uniform base
    gld16(g, l);
  }

  short8 qf0 = *(const short8*)(Q + (size_t)(i0 + li) * 64 + quad * 8);
  short8 qf1 = *(const short8*)(Q + (size_t)(i0 + li) * 64 + 32 + quad * 8);
  __syncthreads();  // K staged

  // ---- S = Q K^T over the 17-tile strip, frags from LDS ----
  floatx4 S[17];
  const int jbase = i0 - SPAN;  // = jb + wv*16
#pragma unroll
  for (int t = 0; t < 17; ++t) {
    int j0 = jbase + t * 16;
    floatx4 acc = {0.f, 0.f, 0.f, 0.f};
    if (j0 > -16 && j0 < L_SEQ) {
      int jrel = (wv + t) * 16;
      short8 kf0 = *(const short8*)&K0[(jrel + li) * 32 + quad * 8];
      short8 kf1 = *(const short8*)&K1[(jrel + li) * 32 + quad * 8];
      acc = __builtin_amdgcn_mfma_f32_16x16x32_bf16(qf0, kf0, acc, 0, 0, 0);
      acc = __builtin_amdgcn_mfma_f32_16x16x32_bf16(qf1, kf1, acc, 0, 0, 0);
    }
    S[t] = acc;
  }
  // scale + band mask + row max  (C-layout: row = quad*4+r, col = li)
  float mrow[4] = {-1e30f, -1e30f, -1e30f, -1e30f};
#pragma unroll
  for (int t = 0; t < 17; ++t) {
    int j = jbase + t * 16 + li;
#pragma unroll
    for (int r = 0; r < 4; ++r) {
      int i = i0 + quad * 4 + r;
      bool inband = (j >= i - SPAN) && (j <= i + SPAN) && (j >= 0) && (j < L_SEQ);
      float s = inband ? S[t][r] * 0.125f : -1e30f;
      S[t][r] = s;
      mrow[r] = fmaxf(mrow[r], s);
    }
  }
#pragma unroll
  for (int m = 1; m <= 8; m <<= 1)
#pragma unroll
    for (int r = 0; r < 4; ++r) mrow[r] = fmaxf(mrow[r], __shfl_xor(mrow[r], m));
  float lsum[4] = {0.f, 0.f, 0.f, 0.f};
#pragma unroll
  for (int t = 0; t < 17; ++t)
#pragma unroll
    for (int r = 0; r < 4; ++r) {
      float p = __expf(S[t][r] - mrow[r]);
      S[t][r] = p;
      lsum[r] += p;
    }
#pragma unroll
  for (int m = 1; m <= 8; m <<= 1)
#pragma unroll
    for (int r = 0; r < 4; ++r) lsum[r] += __shfl_xor(lsum[r], m);
  float inv[4];
#pragma unroll
  for (int r = 0; r < 4; ++r) inv[r] = 1.0f / lsum[r];

  __syncthreads();  // all waves done reading K -> reuse sbuf for P strips
  short* myP = sbuf + wv * 4736;  // 16 rows x 296 (288 + 8 pad) shorts
#pragma unroll
  for (int t = 0; t < 17; ++t)
#pragma unroll
    for (int r = 0; r < 4; ++r)
      myP[(quad * 4 + r) * 296 + t * 16 + li] = f32_bf16(S[t][r] * inv[r]);
  // zero pad cols 272..287
  *(short4*)&myP[(lane >> 2) * 296 + 272 + (lane & 3) * 4] = short4{0, 0, 0, 0};
  __syncthreads();

  // ---- O = P (16x288) x V (288x64); B-frag from V^T global ----
  floatx4 O[4] = {};
#pragma unroll
  for (int c = 0; c < 9; ++c) {
    short8 pf = *(const short8*)&myP[li * 296 + c * 32 + quad * 8];
    int jg = jbase + c * 32 + quad * 8;
    int jc = (jg >= 0 && jg < L_SEQ) ? jg : 0;  // clamp: P is 0 there anyway
#pragma unroll
    for (int n = 0; n < 4; ++n) {
      short8 vf = *(const short8*)(VT + (size_t)(n * 16 + li) * L_SEQ + jc);
      O[n] = __builtin_amdgcn_mfma_f32_16x16x32_bf16(pf, vf, O[n], 0, 0, 0);
    }
  }
  const int b = hb & 1, h = hb >> 1;
#pragma unroll
  for (int n = 0; n < 4; ++n)
#pragma unroll
    for (int r = 0; r < 4; ++r) {
      int irow = quad * 4 + r;
      ctx[((size_t)(i0 + irow) * BB + b) * DD + h * 64 + n * 16 + li] = f32_bf16(O[n][r]);
    }

  // ---- coalesced full-row attn writes (nontemporal; zeros outside band) ----
#pragma unroll 4
  for (int row = 0; row < 16; ++row) {
    float* orow = Aout + (size_t)(i0 + row) * L_SEQ;
    const short* prow = &myP[row * 296];
#pragma unroll
    for (int it = 0; it < 8; ++it) {
      int col = it * 256 + lane * 4;
      int s = col - jbase;
      floatx4 v = {0.f, 0.f, 0.f, 0.f};
      if (s >= 0 && s < 288) {
        short4 p4 = *(const short4*)(prow + s);
        v.x = bf2f(p4.x); v.y = bf2f(p4.y); v.z = bf2f(p4.z); v.w = bf2f(p4.w);
      }
      __builtin_nontemporal_store(v, (floatx4*)(orow + col));
    }
  }
}

// ---------------- FC GEMM + bias + residual ---------------------------------
__global__ __launch_bounds__(256) void k_fc(
    const short* __restrict__ ctx, const short* __restrict__ WfcT,
    const float* __restrict__ bfc, const float* __restrict__ query,
    float* __restrict__ ypre) {
  floatx4 acc[4][4] = {};
  int bm0 = blockIdx.y * BM, bn0 = blockIdx.x * BN;
  gemm_core(ctx, WfcT, acc, bm0, bn0);
  int tid = threadIdx.x;
  int wave = tid >> 6, lane = tid & 63;
  int li = lane & 15, quad = lane >> 4;
  int wm = (wave & 1) * 64, wn = (wave >> 1) * 64;
#pragma unroll
  for (int tm = 0; tm < 4; ++tm)
#pragma unroll
    for (int tn = 0; tn < 4; ++tn) {
      int gn = bn0 + wn + tn * 16 + li;
      float bs = bfc[gn];
#pragma unroll
      for (int r = 0; r < 4; ++r) {
        int gm = bm0 + wm + tm * 16 + quad * 4 + r;
        ypre[(size_t)gm * DD + gn] = acc[tm][tn][r] + bs + query[(size_t)gm * DD + gn];
      }
    }
}

// ---------------- LayerNorm --------------------------------------------------
__global__ __launch_bounds__(256) void k_ln(
    const float* __restrict__ yp, const float* __restrict__ gamma,
    const float* __restrict__ beta, float* __restrict__ out) {
  __shared__ float red[8];
  int row = blockIdx.x, tid = threadIdx.x;
  float4 v = ((const float4*)(yp + (size_t)row * DD))[tid];
  float s = v.x + v.y + v.z + v.w;
  float s2 = v.x * v.x + v.y * v.y + v.z * v.z + v.w * v.w;
#pragma unroll
  for (int m = 1; m <= 32; m <<= 1) {
    s += __shfl_xor(s, m);
    s2 += __shfl_xor(s2, m);
  }
  int wv = tid >> 6;
  if ((tid & 63) == 0) { red[wv] = s; red[wv + 4] = s2; }
  __syncthreads();
  s = red[0] + red[1] + red[2] + red[3];
  s2 = red[4] + red[5] + red[6] + red[7];
  float mu = s * (1.0f / DD);
  float var = s2 * (1.0f / DD) - mu * mu;
  float rs = rsqrtf(var + 1e-5f);
  float4 g = ((const float4*)gamma)[tid];
  float4 bb = ((const float4*)beta)[tid];
  float4 o;
  o.x = (v.x - mu) * rs * g.x + bb.x;
  o.y = (v.y - mu) * rs * g.y + bb.y;
  o.z = (v.z - mu) * rs * g.z + bb.z;
  o.w = (v.w - mu) * rs * g.w + bb.w;
  ((float4*)(out + (size_t)row * DD))[tid] = o;
}

// ---------------- launch -----------------------------------------------------
extern "C" void kernel_launch(void* const* d_in, const int* in_sizes, int n_in,
                              void* d_out, int out_size, void* d_ws, size_t ws_size,
                              hipStream_t stream) {
  const float* query = (const float*)d_in[0];
  const float* key   = (const float*)d_in[1];
  const float* value = (const float*)d_in[2];
  const float* Wq    = (const float*)d_in[3];
  const float* bq    = (const float*)d_in[4];
  const float* Wk    = (const float*)d_in[5];
  const float* bk    = (const float*)d_in[6];
  const float* Wv    = (const float*)d_in[7];
  const float* bv    = (const float*)d_in[8];
  const float* Wfc   = (const float*)d_in[9];
  const float* bfc   = (const float*)d_in[10];
  const float* gamma = (const float*)d_in[11];
  const float* beta  = (const float*)d_in[12];
  float* out = (float*)d_out;
  float* attn = out + (size_t)L_SEQ * BB * DD;  // y first (4194304), then attn

  // workspace layout (88 MB)
  char* w = (char*)d_ws;
  short* xq_b  = (short*)(w);
  short* xk_b  = (short*)(w + ((size_t)8 << 20));
  short* xv_b  = (short*)(w + ((size_t)16 << 20));
  short* WT    = (short*)(w + ((size_t)24 << 20));  // WqT,WkT,WvT,WfcT bf16 (2MB each)
  short* q_ws  = (short*)(w + ((size_t)32 << 20));
  short* k_ws  = (short*)(w + ((size_t)40 << 20));
  short* v_lin = (short*)(w + ((size_t)48 << 20));
  short* vT_ws = (short*)(w + ((size_t)56 << 20));
  short* ctx   = (short*)(w + ((size_t)64 << 20));
  float* ypre  = (float*)(w + ((size_t)72 << 20));

  k_prep<<<16384, 256, 0, stream>>>(query, key, value, Wq, Wk, Wv, Wfc,
                                    xq_b, xk_b, xv_b, WT);
  k_proj<<<dim3(8, 32, 3), 256, 0, stream>>>(xq_b, xk_b, xv_b, WT, bq, bk, bv, q_ws, k_ws, v_lin);
  k_vt<<<dim3(32, 32), 256, 0, stream>>>(v_lin, vT_ws);
  k_attn<<<dim3(32, 32), 256, 0, stream>>>(q_ws, k_ws, vT_ws, attn, ctx);
  k_fc<<<dim3(8, 32), 256, 0, stream>>>(ctx, WT + (size_t)3 * DD * DD, bfc, query, ypre);
  k_ln<<<4096, 256, 0, stream>>>(ypre, gamma, beta, out);
}